// Round 1
// baseline (100963.696 us; speedup 1.0000x reference)
//
#include <hip/hip_runtime.h>
#include <hip/hip_cooperative_groups.h>

namespace cg = cooperative_groups;

#define B    64
#define T    512
#define H    600
#define G3   1800
#define IN0  300
#define KB   150    // k-chunk size (divides 300, 600, 900, 1200)
#define NBLK 150    // blocks: each owns 4 j-values (150*4 = 600)
#define NTHR 256    // threads: (b=64) x (jj=4)

// ws layout (floats)
#define WC0_OFF 0
#define WC0_SZ  (900 * G3)
#define WC1_OFF (WC0_OFF + WC0_SZ)
#define WC1_SZ  (1200 * G3)
#define BC0_OFF (WC1_OFF + WC1_SZ)
#define BC1_OFF (BC0_OFF + H * 4)
#define HA_OFF  (BC1_OFF + H * 4)
#define HB_OFF  (HA_OFF + B * H)
#define WS_FLOATS (HB_OFF + B * H)

// Pack combined weights: WC[k][j*3+gate], k in [0, in_dim+H).
// Rows [0,in_dim) = W_ih^T, rows [in_dim, in_dim+H) = W_hh^T.
__global__ void build_wc(const float* __restrict__ Wih, const float* __restrict__ Whh,
                         float* __restrict__ WC, int in_dim, int ktot) {
    int idx = blockIdx.x * blockDim.x + threadIdx.x;
    if (idx >= ktot * G3) return;
    int k = idx / G3;
    int c = idx - k * G3;
    int j = c / 3;
    int g = c - j * 3;
    int grow = g * H + j;  // row in original (3H x in) weight
    float v = (k < in_dim) ? Wih[grow * in_dim + k] : Whh[grow * H + (k - in_dim)];
    WC[idx] = v;
}

// Pack biases: BC[j] = {b_ih_r+b_hh_r, b_ih_z+b_hh_z, b_ih_n, b_hh_n}
__global__ void build_bc(const float* __restrict__ bih0, const float* __restrict__ bhh0,
                         const float* __restrict__ bih1, const float* __restrict__ bhh1,
                         float* __restrict__ BC0, float* __restrict__ BC1) {
    int j = blockIdx.x * blockDim.x + threadIdx.x;
    if (j >= H) return;
    BC0[j * 4 + 0] = bih0[j] + bhh0[j];
    BC0[j * 4 + 1] = bih0[H + j] + bhh0[H + j];
    BC0[j * 4 + 2] = bih0[2 * H + j];
    BC0[j * 4 + 3] = bhh0[2 * H + j];
    BC1[j * 4 + 0] = bih1[j] + bhh1[j];
    BC1[j * 4 + 1] = bih1[H + j] + bhh1[H + j];
    BC1[j * 4 + 2] = bih1[2 * H + j];
    BC1[j * 4 + 3] = bhh1[2 * H + j];
}

// Cooperative GRU: 150 blocks x 256 threads, one grid.sync per timestep.
// NOTE: x0/ret deliberately NOT __restrict__ (layer1 reads+writes ret).
__global__ void __launch_bounds__(NTHR, 1) gru_main(
    const float* x0, const float* __restrict__ hid,
    const float* __restrict__ WC0, const float* __restrict__ WC1,
    const float* __restrict__ BC0, const float* __restrict__ BC1,
    float* __restrict__ hA, float* __restrict__ hB,
    float* ret, float* __restrict__ outh) {
    cg::grid_group grid = cg::this_grid();
    const int tid = threadIdx.x;
    const int bb = tid >> 2;              // batch 0..63
    const int jj = tid & 3;               // j within block slice
    const int j = blockIdx.x * 4 + jj;    // 0..599
    const int jj3 = jj * 3;
    const int wcol0 = blockIdx.x * 12;    // 12 contiguous WC columns per block

    __shared__ float At[B * (KB + 1)];    // +1 pad: kills 16-way bank conflict on At[bb][kk]
    __shared__ float Wt[KB * 12];

    for (int layer = 0; layer < 2; ++layer) {
        const int in_dim = layer ? H : IN0;
        const int nch = (in_dim + H) / KB;
        const int gich = in_dim / KB;      // chunks in the gi (x) phase
        const float* xsrc = layer ? ret : x0;
        const int xst = layer ? H : IN0;
        const float* WC = layer ? WC1 : WC0;
        const float* BC = layer ? BC1 : BC0;

        // init h: grid covers exactly B*H = 38400 elements
        {
            int gidx = blockIdx.x * NTHR + tid;
            hA[gidx] = hid[layer * (B * H) + gidx];
        }
        grid.sync();

        float* hc = hA;
        float* hn = hB;
        const float bx = BC[j * 4 + 0];
        const float by = BC[j * 4 + 1];
        const float bgn = BC[j * 4 + 2];
        const float bhn = BC[j * 4 + 3];
        float hold = 0.0f;   // layer1 lag-write buffer (register)
        float hnv = 0.0f;

        for (int t = 0; t < T; ++t) {
            float sr = 0.f, sz = 0.f, sgn = 0.f, shn = 0.f;
            for (int ci = 0; ci < nch; ++ci) {
                const int k0 = ci * KB;
                __syncthreads();  // previous chunk consumed
                if (ci < gich) {
                    // stage x_t slice: At[b][c] = x[b][t][k0+c]
                    for (int idx = tid; idx < B * KB; idx += NTHR) {
                        int row = idx / KB;
                        int col = idx - row * KB;
                        At[row * (KB + 1) + col] =
                            xsrc[((size_t)row * T + t) * xst + (k0 + col)];
                    }
                } else {
                    // stage h slice: At[b][c] = h[b][k0-in_dim+c]
                    const int hk0 = k0 - in_dim;
                    for (int idx = tid; idx < B * KB; idx += NTHR) {
                        int row = idx / KB;
                        int col = idx - row * KB;
                        At[row * (KB + 1) + col] = hc[row * H + hk0 + col];
                    }
                }
                for (int idx = tid; idx < KB * 12; idx += NTHR) {
                    int kk = idx / 12;
                    int cc = idx - kk * 12;
                    Wt[idx] = WC[(size_t)(k0 + kk) * G3 + wcol0 + cc];
                }
                __syncthreads();
                const float* arow = &At[bb * (KB + 1)];
                if (ci < gich) {
                    #pragma unroll 5
                    for (int kk = 0; kk < KB; ++kk) {
                        float a = arow[kk];
                        const float* w = &Wt[kk * 12 + jj3];
                        sr += a * w[0];
                        sz += a * w[1];
                        sgn += a * w[2];
                    }
                } else {
                    #pragma unroll 5
                    for (int kk = 0; kk < KB; ++kk) {
                        float a = arow[kk];
                        const float* w = &Wt[kk * 12 + jj3];
                        sr += a * w[0];
                        sz += a * w[1];
                        shn += a * w[2];
                    }
                }
            }
            float r = 1.f / (1.f + __expf(-(sr + bx)));
            float z = 1.f / (1.f + __expf(-(sz + by)));
            float n = tanhf(sgn + bgn + r * (shn + bhn));
            float hv = hc[bb * H + j];
            hnv = (1.f - z) * n + z * hv;
            hn[bb * H + j] = hnv;
            if (layer == 0) {
                ret[((size_t)bb * T + t) * H + j] = hnv;  // layer0 out seq -> d_out (read by layer1)
            } else {
                // lag-write: slot t-1 was last READ before the previous grid.sync -> safe now
                if (t > 0) ret[((size_t)bb * T + (t - 1)) * H + j] = hold;
                hold = hnv;
            }
            grid.sync();
            float* tmp = hc; hc = hn; hn = tmp;
        }
        if (layer == 1) {
            ret[((size_t)bb * T + (T - 1)) * H + j] = hold;  // flush last slot
        }
        outh[layer * (B * H) + bb * H + j] = hnv;  // final hidden
        grid.sync();
    }
}

extern "C" void kernel_launch(void* const* d_in, const int* in_sizes, int n_in,
                              void* d_out, int out_size, void* d_ws, size_t ws_size,
                              hipStream_t stream) {
    const float* x0   = (const float*)d_in[0];  // (64,512,300)
    const float* hid  = (const float*)d_in[1];  // (2,64,600)
    const float* Wih0 = (const float*)d_in[2];  // (1800,300)
    const float* Whh0 = (const float*)d_in[3];  // (1800,600)
    const float* bih0 = (const float*)d_in[4];
    const float* bhh0 = (const float*)d_in[5];
    const float* Wih1 = (const float*)d_in[6];  // (1800,600)
    const float* Whh1 = (const float*)d_in[7];
    const float* bih1 = (const float*)d_in[8];
    const float* bhh1 = (const float*)d_in[9];

    float* ws  = (float*)d_ws;
    float* WC0 = ws + WC0_OFF;
    float* WC1 = ws + WC1_OFF;
    float* BC0 = ws + BC0_OFF;
    float* BC1 = ws + BC1_OFF;
    float* hA  = ws + HA_OFF;
    float* hB  = ws + HB_OFF;

    float* ret  = (float*)d_out;
    float* outh = ret + (size_t)B * T * H;

    // prep: pack weights (re-done every call; ws is re-poisoned by harness)
    {
        int n0 = 900 * G3;
        build_wc<<<(n0 + 255) / 256, 256, 0, stream>>>(Wih0, Whh0, WC0, IN0, 900);
        int n1 = 1200 * G3;
        build_wc<<<(n1 + 255) / 256, 256, 0, stream>>>(Wih1, Whh1, WC1, H, 1200);
        build_bc<<<(H + 255) / 256, 256, 0, stream>>>(bih0, bhh0, bih1, bhh1, BC0, BC1);
    }

    void* x0v = (void*)x0; void* hidv = (void*)hid;
    void* wc0v = (void*)WC0; void* wc1v = (void*)WC1;
    void* bc0v = (void*)BC0; void* bc1v = (void*)BC1;
    void* hAv = (void*)hA; void* hBv = (void*)hB;
    void* retv = (void*)ret; void* outhv = (void*)outh;
    void* args[] = {&x0v, &hidv, &wc0v, &wc1v, &bc0v, &bc1v, &hAv, &hBv, &retv, &outhv};
    hipLaunchCooperativeKernel((void*)gru_main, dim3(NBLK), dim3(NTHR), args, 0, stream);
}

// Round 4
// 28518.533 us; speedup vs baseline: 3.5403x; 3.5403x over previous
//
#include <hip/hip_runtime.h>

#define B    64
#define T    512
#define H    600
#define G3   1800
#define IN0  300
#define NBLK 150    // blocks: each owns 4 j-values (150*4 = 600); <= 256 CUs
#define NTHR 256    // threads: (b=64) x (jj=4)
#define KPAD 1208   // LDS row stride (floats): 3*KPAD % 32 == 8 -> the 4 jj base
                    // addresses land on banks {0,8,16,24}; b128 reads cover 16
                    // disjoint banks, broadcast across lanes -> conflict-free.
// Static LDS = 12*1208*4 = 57,984 B < 65,536 static limit (plain launch; no
// cooperative-launch validation to fail).

// ws layout (floats)
#define WC0_OFF 0
#define WC0_SZ  (900 * G3)
#define WC1_OFF (WC0_OFF + WC0_SZ)
#define WC1_SZ  (1200 * G3)
#define BC0_OFF (WC1_OFF + WC1_SZ)
#define BC1_OFF (BC0_OFF + H * 4)
#define HA_OFF  (BC1_OFF + H * 4)
#define HB_OFF  (HA_OFF + B * H)
#define BAR_OFF (HB_OFF + B * H + 64)   // int area; cnt at +0, gen at +32 (sep. cachelines)

// ---------------- software grid barrier (plain launch, agent-scope atomics) ----
__device__ __forceinline__ void grid_barrier(int* __restrict__ cnt, int* __restrict__ gen) {
    __syncthreads();
    if (threadIdx.x == 0) {
        int g = __hip_atomic_load(gen, __ATOMIC_RELAXED, __HIP_MEMORY_SCOPE_AGENT);
        int arrived = __hip_atomic_fetch_add(cnt, 1, __ATOMIC_ACQ_REL, __HIP_MEMORY_SCOPE_AGENT);
        if (arrived == NBLK - 1) {
            // all arrived; reset count BEFORE releasing the generation
            __hip_atomic_store(cnt, 0, __ATOMIC_RELAXED, __HIP_MEMORY_SCOPE_AGENT);
            __hip_atomic_fetch_add(gen, 1, __ATOMIC_ACQ_REL, __HIP_MEMORY_SCOPE_AGENT);
        } else {
            while (__hip_atomic_load(gen, __ATOMIC_ACQUIRE, __HIP_MEMORY_SCOPE_AGENT) == g) {
                __builtin_amdgcn_s_sleep(1);
            }
        }
    }
    __syncthreads();
}

__global__ void init_bar(int* bar) { bar[0] = 0; bar[32] = 0; }

// Pack combined weights: WC[k][j*3+gate], k in [0, in_dim+H).
__global__ void build_wc(const float* __restrict__ Wih, const float* __restrict__ Whh,
                         float* __restrict__ WC, int in_dim, int ktot) {
    int idx = blockIdx.x * blockDim.x + threadIdx.x;
    if (idx >= ktot * G3) return;
    int k = idx / G3;
    int c = idx - k * G3;
    int j = c / 3;
    int g = c - j * 3;
    int grow = g * H + j;
    float v = (k < in_dim) ? Wih[grow * in_dim + k] : Whh[grow * H + (k - in_dim)];
    WC[idx] = v;
}

__global__ void build_bc(const float* __restrict__ bih0, const float* __restrict__ bhh0,
                         const float* __restrict__ bih1, const float* __restrict__ bhh1,
                         float* __restrict__ BC0, float* __restrict__ BC1) {
    int j = blockIdx.x * blockDim.x + threadIdx.x;
    if (j >= H) return;
    BC0[j * 4 + 0] = bih0[j] + bhh0[j];
    BC0[j * 4 + 1] = bih0[H + j] + bhh0[H + j];
    BC0[j * 4 + 2] = bih0[2 * H + j];
    BC0[j * 4 + 3] = bhh0[2 * H + j];
    BC1[j * 4 + 0] = bih1[j] + bhh1[j];
    BC1[j * 4 + 1] = bih1[H + j] + bhh1[H + j];
    BC1[j * 4 + 2] = bih1[2 * H + j];
    BC1[j * 4 + 3] = bhh1[2 * H + j];
}

// Triple fp32 dot over N4 float4s. a: global, double-buffered register pipeline
// (CH float4 in flight). w: LDS float4 broadcast reads. #pragma unroll 1 keeps
// ONE copy of the ping-pong body (bounded register pressure).
template<int N4, int CH>
__device__ __forceinline__ void dot3f(const float4* __restrict__ ap,
                                      const float* __restrict__ wr,
                                      const float* __restrict__ wz,
                                      const float* __restrict__ wn,
                                      float& sr, float& sz, float& sn) {
    constexpr int NCH = N4 / CH;
    static_assert(N4 % CH == 0, "chunking");
    float4 A[CH], Bf[CH];
    #pragma unroll
    for (int i = 0; i < CH; ++i) A[i] = ap[i];
    #pragma unroll 1
    for (int c = 0; c < NCH; c += 2) {
        if (c + 1 < NCH) {
            const float4* p = ap + (c + 1) * CH;
            #pragma unroll
            for (int i = 0; i < CH; ++i) Bf[i] = p[i];
        }
        #pragma unroll
        for (int i = 0; i < CH; ++i) {
            const int k = (c * CH + i) * 4;
            float4 a = A[i];
            const float4 wR = *(const float4*)(wr + k);
            const float4 wZ = *(const float4*)(wz + k);
            const float4 wN = *(const float4*)(wn + k);
            sr += a.x * wR.x + a.y * wR.y + a.z * wR.z + a.w * wR.w;
            sz += a.x * wZ.x + a.y * wZ.y + a.z * wZ.z + a.w * wZ.w;
            sn += a.x * wN.x + a.y * wN.y + a.z * wN.z + a.w * wN.w;
        }
        if (c + 1 < NCH) {
            if (c + 2 < NCH) {
                const float4* p = ap + (c + 2) * CH;
                #pragma unroll
                for (int i = 0; i < CH; ++i) A[i] = p[i];
            }
            #pragma unroll
            for (int i = 0; i < CH; ++i) {
                const int k = ((c + 1) * CH + i) * 4;
                float4 a = Bf[i];
                const float4 wR = *(const float4*)(wr + k);
                const float4 wZ = *(const float4*)(wz + k);
                const float4 wN = *(const float4*)(wn + k);
                sr += a.x * wR.x + a.y * wR.y + a.z * wR.z + a.w * wR.w;
                sz += a.x * wZ.x + a.y * wZ.y + a.z * wZ.z + a.w * wZ.w;
                sn += a.x * wN.x + a.y * wN.y + a.z * wN.z + a.w * wN.w;
            }
        }
    }
}

template<int LAYER>
__device__ void gru_layer(const float* xsrc, const float* __restrict__ hid,
                          const float* __restrict__ WC, const float* __restrict__ BC,
                          float* __restrict__ hA, float* __restrict__ hB,
                          float* ret, float* __restrict__ outh,
                          float* Wl, int* cnt, int* gen) {
    constexpr int IN_DIM = LAYER ? H : IN0;
    constexpr int K = IN_DIM + H;
    const int tid = threadIdx.x;
    const int bb = tid >> 2;
    const int jj = tid & 3;
    const int j = blockIdx.x * 4 + jj;
    const int wcol0 = blockIdx.x * 12;

    // Load this block's 12 W columns (full K) into LDS once per layer.
    // Wl is per-block LDS: only our own waves matter -> __syncthreads suffices
    // for Wl; the grid barrier below covers the hA init (global).
    for (int idx = tid; idx < 12 * K; idx += NTHR) {
        int k = idx / 12;
        int c = idx - k * 12;
        Wl[c * KPAD + k] = WC[(size_t)k * G3 + wcol0 + c];
    }
    {
        int g = blockIdx.x * NTHR + tid;   // grid covers exactly B*H = 38400
        hA[g] = hid[g];
    }
    grid_barrier(cnt, gen);   // includes __syncthreads for the Wl load

    float* hc = hA;
    float* hn = hB;
    const float bx  = BC[j * 4 + 0];
    const float by  = BC[j * 4 + 1];
    const float bgn = BC[j * 4 + 2];
    const float bhn = BC[j * 4 + 3];
    const float* wr = &Wl[(jj * 3 + 0) * KPAD];
    const float* wz = &Wl[(jj * 3 + 1) * KPAD];
    const float* wn = &Wl[(jj * 3 + 2) * KPAD];
    float hold = 0.0f;
    float hnv = 0.0f;

    for (int t = 0; t < T; ++t) {
        float sr = 0.f, sz = 0.f, sgn = 0.f, shn = 0.f;
        dot3f<IN_DIM / 4, 15>((const float4*)(xsrc + ((size_t)bb * T + t) * IN_DIM),
                              wr, wz, wn, sr, sz, sgn);
        dot3f<H / 4, 15>((const float4*)(hc + bb * H),
                         wr + IN_DIM, wz + IN_DIM, wn + IN_DIM, sr, sz, shn);
        float r = 1.f / (1.f + __expf(-(sr + bx)));
        float z = 1.f / (1.f + __expf(-(sz + by)));
        float n = tanhf(sgn + bgn + r * (shn + bhn));
        float hv = hc[bb * H + j];
        hnv = (1.f - z) * n + z * hv;
        hn[bb * H + j] = hnv;
        if (LAYER == 0) {
            ret[((size_t)bb * T + t) * H + j] = hnv;       // layer0 seq -> d_out
        } else {
            // lag-write: slot t-1 was last read during step t-1, a barrier ago
            if (t > 0) ret[((size_t)bb * T + (t - 1)) * H + j] = hold;
            hold = hnv;
        }
        grid_barrier(cnt, gen);
        float* tmp = hc; hc = hn; hn = tmp;
    }
    if (LAYER == 1) {
        ret[((size_t)bb * T + (T - 1)) * H + j] = hold;
    }
    outh[bb * H + j] = hnv;
    grid_barrier(cnt, gen);   // layer0 ret fully written before layer1 reads it;
                              // Wl safe to overwrite
}

__global__ void __launch_bounds__(NTHR, 1) gru_main(
    const float* x0, const float* __restrict__ hid,
    const float* __restrict__ WC0, const float* __restrict__ WC1,
    const float* __restrict__ BC0, const float* __restrict__ BC1,
    float* __restrict__ hA, float* __restrict__ hB,
    float* ret, float* __restrict__ outh, int* bar) {
    __shared__ __align__(16) float Wl[12 * KPAD];   // 57,984 B
    int* cnt = bar;
    int* gen = bar + 32;
    gru_layer<0>(x0, hid,          WC0, BC0, hA, hB, ret, outh,         Wl, cnt, gen);
    gru_layer<1>(ret, hid + B * H, WC1, BC1, hA, hB, ret, outh + B * H, Wl, cnt, gen);
}

extern "C" void kernel_launch(void* const* d_in, const int* in_sizes, int n_in,
                              void* d_out, int out_size, void* d_ws, size_t ws_size,
                              hipStream_t stream) {
    const float* x0   = (const float*)d_in[0];
    const float* hid  = (const float*)d_in[1];
    const float* Wih0 = (const float*)d_in[2];
    const float* Whh0 = (const float*)d_in[3];
    const float* bih0 = (const float*)d_in[4];
    const float* bhh0 = (const float*)d_in[5];
    const float* Wih1 = (const float*)d_in[6];
    const float* Whh1 = (const float*)d_in[7];
    const float* bih1 = (const float*)d_in[8];
    const float* bhh1 = (const float*)d_in[9];

    float* ws  = (float*)d_ws;
    float* WC0 = ws + WC0_OFF;
    float* WC1 = ws + WC1_OFF;
    float* BC0 = ws + BC0_OFF;
    float* BC1 = ws + BC1_OFF;
    float* hA  = ws + HA_OFF;
    float* hB  = ws + HB_OFF;
    int*   bar = (int*)(ws + BAR_OFF);

    float* ret  = (float*)d_out;
    float* outh = ret + (size_t)B * T * H;

    {
        int n0 = 900 * G3;
        build_wc<<<(n0 + 255) / 256, 256, 0, stream>>>(Wih0, Whh0, WC0, IN0, 900);
        int n1 = 1200 * G3;
        build_wc<<<(n1 + 255) / 256, 256, 0, stream>>>(Wih1, Whh1, WC1, H, 1200);
        build_bc<<<(H + 255) / 256, 256, 0, stream>>>(bih0, bhh0, bih1, bhh1, BC0, BC1);
        init_bar<<<1, 1, 0, stream>>>(bar);
    }

    gru_main<<<dim3(NBLK), dim3(NTHR), 0, stream>>>(
        x0, hid, WC0, WC1, BC0, BC1, hA, hB, ret, outh, bar);
}